// Round 1
// baseline (460.483 us; speedup 1.0000x reference)
//
#include <hip/hip_runtime.h>

// Problem constants (fixed by the reference)
#define N_NODES 20000
#define N_EDGES 320000
#define ETOT    (N_EDGES + N_NODES)   // edges + self-loops = 340000
#define HEADS   10
#define F_IN    32
#define C1      (HEADS * F_IN)        // 320
#define C2      128
#define NB      100
#define PER     200

// ---------------------------------------------------------------------------
// CSR-by-destination construction (shared by both GAT layers)
// ---------------------------------------------------------------------------
__global__ void hist_kernel(const int* __restrict__ ei, int* __restrict__ counts) {
    int e = blockIdx.x * blockDim.x + threadIdx.x;
    if (e >= ETOT) return;
    int d = (e < N_EDGES) ? ei[N_EDGES + e] : (e - N_EDGES);  // row1 = dst; self-loops
    atomicAdd(&counts[d], 1);
}

__global__ void scan_kernel(const int* __restrict__ counts, int* __restrict__ row_start) {
    __shared__ int sums[1024];
    int tid = threadIdx.x;
    const int per = (N_NODES + 1023) / 1024;  // 20
    int base = tid * per;
    int s = 0;
    for (int i = 0; i < per; i++) {
        int idx = base + i;
        if (idx < N_NODES) s += counts[idx];
    }
    sums[tid] = s;
    __syncthreads();
    for (int off = 1; off < 1024; off <<= 1) {
        int v = (tid >= off) ? sums[tid - off] : 0;
        __syncthreads();
        sums[tid] += v;
        __syncthreads();
    }
    int run = (tid == 0) ? 0 : sums[tid - 1];
    for (int i = 0; i < per; i++) {
        int idx = base + i;
        if (idx < N_NODES) { row_start[idx] = run; run += counts[idx]; }
    }
    if (tid == 1023) row_start[N_NODES] = run;  // = ETOT
}

__global__ void scatter_kernel(const int* __restrict__ ei, const int* __restrict__ row_start,
                               int* __restrict__ cursor, int* __restrict__ csr_src) {
    int e = blockIdx.x * blockDim.x + threadIdx.x;
    if (e >= ETOT) return;
    int s, d;
    if (e < N_EDGES) { s = ei[e]; d = ei[N_EDGES + e]; }
    else             { s = e - N_EDGES; d = s; }
    int pos = atomicAdd(&cursor[d], 1);
    csr_src[row_start[d] + pos] = s;
}

// ---------------------------------------------------------------------------
// Layer 1: xw1 = feats @ W1  [N,320], plus attention scores s_src/s_dst [N,10]
// block: 320 threads (thread t = h*32+f), 8 nodes per block
// ---------------------------------------------------------------------------
__global__ void gemm1_kernel(const float* __restrict__ x, const float* __restrict__ W1,
                             const float* __restrict__ a_src, const float* __restrict__ a_dst,
                             float* __restrict__ xw1, float* __restrict__ s_src,
                             float* __restrict__ s_dst) {
    __shared__ float w[F_IN * C1];   // 40 KB
    __shared__ float xr[8][F_IN];
    int t = threadIdx.x;
    for (int i = t; i < F_IN * C1; i += C1) w[i] = W1[i];
    int n0 = blockIdx.x * 8;
    for (int i = t; i < 8 * F_IN; i += C1) {
        int r = i >> 5, c = i & 31;
        xr[r][c] = x[(n0 + r) * F_IN + c];
    }
    __syncthreads();
    int h = t >> 5, f = t & 31;
    float as = a_src[t];   // a_src[h][f]
    float ad = a_dst[t];
    for (int r = 0; r < 8; r++) {
        int n = n0 + r;
        float acc = 0.f;
#pragma unroll
        for (int k = 0; k < F_IN; k++) acc += xr[r][k] * w[k * C1 + t];
        xw1[n * C1 + t] = acc;
        // reduce over f within each 32-lane half (head)
        float vs = acc * as, vd = acc * ad;
#pragma unroll
        for (int off = 16; off >= 1; off >>= 1) {
            vs += __shfl_xor(vs, off);
            vd += __shfl_xor(vd, off);
        }
        if (f == 0) { s_src[n * HEADS + h] = vs; s_dst[n * HEADS + h] = vd; }
    }
}

// ---------------------------------------------------------------------------
// Layer 1 aggregation: per-node online softmax over incoming edges + ELU
// block: 320 threads (t = h*32+f), one node per block
// ---------------------------------------------------------------------------
__global__ void agg1_kernel(const float* __restrict__ xw1, const float* __restrict__ s_src,
                            const float* __restrict__ s_dst, const int* __restrict__ row_start,
                            const int* __restrict__ csr_src, const float* __restrict__ b1,
                            float* __restrict__ h1) {
    int n = blockIdx.x;
    int t = threadIdx.x;
    int h = t >> 5;
    int beg = row_start[n], end = row_start[n + 1];
    float sd = s_dst[n * HEADS + h];
    float m = -1e30f, l = 0.f, acc = 0.f;
    for (int i = beg; i < end; i++) {
        int s = csr_src[i];
        float e = s_src[s * HEADS + h] + sd;
        e = (e >= 0.f) ? e : 0.2f * e;           // leaky_relu(0.2)
        float mn = fmaxf(m, e);
        float sc = __expf(m - mn);
        float p  = __expf(e - mn);
        float v  = xw1[s * C1 + t];
        acc = acc * sc + p * v;
        l   = l * sc + p;
        m   = mn;
    }
    float o = acc / fmaxf(l, 1e-16f) + b1[t];
    o = (o > 0.f) ? o : (__expf(o) - 1.f);       // ELU
    h1[n * C1 + t] = o;
}

// ---------------------------------------------------------------------------
// Layer 2 GEMM: xw2 = h1 @ W2  [N,128], plus scalar scores s2_src/s2_dst [N]
// block: 128 threads, 16 node-rows per block, A rows staged in LDS
// ---------------------------------------------------------------------------
__global__ void gemm2_kernel(const float* __restrict__ h1, const float* __restrict__ W2,
                             const float* __restrict__ a_src, const float* __restrict__ a_dst,
                             float* __restrict__ xw2, float* __restrict__ s_src2,
                             float* __restrict__ s_dst2) {
    __shared__ float A[16 * C1];     // 20 KB
    __shared__ float redS[2][16];
    __shared__ float redD[2][16];
    int t = threadIdx.x;
    int n0 = blockIdx.x * 16;
    for (int i = t; i < 16 * C1; i += 128) A[i] = h1[n0 * C1 + i];
    __syncthreads();
    float acc[16];
#pragma unroll
    for (int r = 0; r < 16; r++) acc[r] = 0.f;
    for (int k = 0; k < C1; k++) {
        float b = W2[k * C2 + t];
#pragma unroll
        for (int r = 0; r < 16; r++) acc[r] += A[r * C1 + k] * b;
    }
    float as = a_src[t], ad = a_dst[t];
    int lane = t & 63, wave = t >> 6;
    for (int r = 0; r < 16; r++) {
        xw2[(n0 + r) * C2 + t] = acc[r];
        float vs = acc[r] * as, vd = acc[r] * ad;
#pragma unroll
        for (int off = 32; off >= 1; off >>= 1) {
            vs += __shfl_xor(vs, off);
            vd += __shfl_xor(vd, off);
        }
        if (lane == 0) { redS[wave][r] = vs; redD[wave][r] = vd; }
    }
    __syncthreads();
    if (t < 16)       s_src2[n0 + t]      = redS[0][t] + redS[1][t];
    else if (t < 32)  s_dst2[n0 + t - 16] = redD[0][t - 16] + redD[1][t - 16];
}

// ---------------------------------------------------------------------------
// Layer 2 aggregation (H=1) + ReLU
// ---------------------------------------------------------------------------
__global__ void agg2_kernel(const float* __restrict__ xw2, const float* __restrict__ s_src2,
                            const float* __restrict__ s_dst2, const int* __restrict__ row_start,
                            const int* __restrict__ csr_src, const float* __restrict__ b2,
                            float* __restrict__ x2) {
    int n = blockIdx.x;
    int t = threadIdx.x;   // 128
    int beg = row_start[n], end = row_start[n + 1];
    float sd = s_dst2[n];
    float m = -1e30f, l = 0.f, acc = 0.f;
    for (int i = beg; i < end; i++) {
        int s = csr_src[i];
        float e = s_src2[s] + sd;
        e = (e >= 0.f) ? e : 0.2f * e;
        float mn = fmaxf(m, e);
        float sc = __expf(m - mn);
        float p  = __expf(e - mn);
        acc = acc * sc + p * xw2[s * C2 + t];
        l   = l * sc + p;
        m   = mn;
    }
    float o = acc / fmaxf(l, 1e-16f) + b2[t];
    x2[n * C2 + t] = fmaxf(o, 0.f);              // ReLU
}

// ---------------------------------------------------------------------------
// Main output: relu(x2 @ fc_w + fc_b)  ([B,PER,128] == [N,128], identity split)
// ---------------------------------------------------------------------------
__global__ void fc_main_kernel(const float* __restrict__ x2, const float* __restrict__ fc_w,
                               const float* __restrict__ fc_b, float* __restrict__ out) {
    __shared__ float A[16 * C2];     // 8 KB
    int t = threadIdx.x;
    int n0 = blockIdx.x * 16;
    for (int i = t; i < 16 * C2; i += 128) A[i] = x2[n0 * C2 + i];
    __syncthreads();
    float acc[16];
#pragma unroll
    for (int r = 0; r < 16; r++) acc[r] = 0.f;
    for (int k = 0; k < C2; k++) {
        float b = fc_w[k * C2 + t];
#pragma unroll
        for (int r = 0; r < 16; r++) acc[r] += A[r * C2 + k] * b;
    }
    float bb = fc_b[t];
    for (int r = 0; r < 16; r++)
        out[(n0 + r) * C2 + t] = fmaxf(acc[r] + bb, 0.f);
}

// ---------------------------------------------------------------------------
// Pooling: per-graph max over 200 nodes, then relu(pooled @ fc_w + fc_b)
// ---------------------------------------------------------------------------
__global__ void pool_kernel(const float* __restrict__ x2, float* __restrict__ pooled) {
    int g = blockIdx.x, t = threadIdx.x;   // 128
    float mx = -1e30f;
    for (int i = 0; i < PER; i++)
        mx = fmaxf(mx, x2[(g * PER + i) * C2 + t]);
    pooled[g * C2 + t] = mx;
}

__global__ void fc_pool_kernel(const float* __restrict__ pooled, const float* __restrict__ fc_w,
                               const float* __restrict__ fc_b, float* __restrict__ outp) {
    __shared__ float A[C2];
    int g = blockIdx.x, t = threadIdx.x;
    A[t] = pooled[g * C2 + t];
    __syncthreads();
    float acc = 0.f;
    for (int k = 0; k < C2; k++) acc += A[k] * fc_w[k * C2 + t];
    outp[g * C2 + t] = fmaxf(acc + fc_b[t], 0.f);
}

// ---------------------------------------------------------------------------
extern "C" void kernel_launch(void* const* d_in, const int* in_sizes, int n_in,
                              void* d_out, int out_size, void* d_ws, size_t ws_size,
                              hipStream_t stream) {
    const float* feats = (const float*)d_in[0];
    const int*   ei    = (const int*)d_in[1];
    // d_in[2] graph_id, d_in[3] batch_num_nodes: layout is uniform -> unused
    const float* W1  = (const float*)d_in[4];
    const float* a1s = (const float*)d_in[5];
    const float* a1d = (const float*)d_in[6];
    const float* b1  = (const float*)d_in[7];
    const float* W2  = (const float*)d_in[8];
    const float* a2s = (const float*)d_in[9];
    const float* a2d = (const float*)d_in[10];
    const float* b2  = (const float*)d_in[11];
    const float* fcw = (const float*)d_in[12];
    const float* fcb = (const float*)d_in[13];

    float* out_main = (float*)d_out;                       // [20000,128]
    float* out_pool = (float*)d_out + (size_t)N_NODES * C2; // [100,128]

    char* p = (char*)d_ws;
    auto alloc = [&](size_t bytes) {
        char* r = p;
        p += (bytes + 255) & ~(size_t)255;
        return r;
    };
    float* xw1    = (float*)alloc(sizeof(float) * N_NODES * C1);
    float* h1     = (float*)alloc(sizeof(float) * N_NODES * C1);
    float* s1s    = (float*)alloc(sizeof(float) * N_NODES * HEADS);
    float* s1d    = (float*)alloc(sizeof(float) * N_NODES * HEADS);
    float* xw2    = (float*)alloc(sizeof(float) * N_NODES * C2);
    float* s2s    = (float*)alloc(sizeof(float) * N_NODES);
    float* s2d    = (float*)alloc(sizeof(float) * N_NODES);
    float* x2     = (float*)alloc(sizeof(float) * N_NODES * C2);
    float* pooled = (float*)alloc(sizeof(float) * NB * C2);
    int* counts   = (int*)alloc(sizeof(int) * N_NODES * 2);  // counts + cursor
    int* cursor   = counts + N_NODES;
    int* row_start = (int*)alloc(sizeof(int) * (N_NODES + 1));
    int* csr_src  = (int*)alloc(sizeof(int) * ETOT);

    // zero histogram + scatter cursors (ws is poisoned before every launch)
    hipMemsetAsync(counts, 0, sizeof(int) * N_NODES * 2, stream);

    hist_kernel<<<(ETOT + 255) / 256, 256, 0, stream>>>(ei, counts);
    scan_kernel<<<1, 1024, 0, stream>>>(counts, row_start);
    scatter_kernel<<<(ETOT + 255) / 256, 256, 0, stream>>>(ei, row_start, cursor, csr_src);

    gemm1_kernel<<<N_NODES / 8, C1, 0, stream>>>(feats, W1, a1s, a1d, xw1, s1s, s1d);
    agg1_kernel<<<N_NODES, C1, 0, stream>>>(xw1, s1s, s1d, row_start, csr_src, b1, h1);
    gemm2_kernel<<<N_NODES / 16, C2, 0, stream>>>(h1, W2, a2s, a2d, xw2, s2s, s2d);
    agg2_kernel<<<N_NODES, C2, 0, stream>>>(xw2, s2s, s2d, row_start, csr_src, b2, x2);
    fc_main_kernel<<<N_NODES / 16, C2, 0, stream>>>(x2, fcw, fcb, out_main);
    pool_kernel<<<NB, C2, 0, stream>>>(x2, pooled);
    fc_pool_kernel<<<NB, C2, 0, stream>>>(pooled, fcw, fcb, out_pool);
}

// Round 2
// 398.091 us; speedup vs baseline: 1.1567x; 1.1567x over previous
//
#include <hip/hip_runtime.h>

// Problem constants (fixed by the reference)
#define N_NODES 20000
#define N_EDGES 320000
#define ETOT    (N_EDGES + N_NODES)   // edges + self-loops = 340000
#define HEADS   10
#define F_IN    32
#define C1      (HEADS * F_IN)        // 320
#define C2      128
#define NB      100
#define PER     200
#define MAXDEG  128                   // chunk size for per-node edge lists

// ---------------------------------------------------------------------------
// CSR-by-destination construction (shared by both GAT layers)
// ---------------------------------------------------------------------------
__global__ void hist_kernel(const int* __restrict__ ei, int* __restrict__ counts) {
    int e = blockIdx.x * blockDim.x + threadIdx.x;
    if (e >= ETOT) return;
    int d = (e < N_EDGES) ? ei[N_EDGES + e] : (e - N_EDGES);  // row1 = dst; self-loops
    atomicAdd(&counts[d], 1);
}

__global__ void scan_kernel(const int* __restrict__ counts, int* __restrict__ row_start) {
    __shared__ int sums[1024];
    int tid = threadIdx.x;
    const int per = (N_NODES + 1023) / 1024;  // 20
    int base = tid * per;
    int s = 0;
    for (int i = 0; i < per; i++) {
        int idx = base + i;
        if (idx < N_NODES) s += counts[idx];
    }
    sums[tid] = s;
    __syncthreads();
    for (int off = 1; off < 1024; off <<= 1) {
        int v = (tid >= off) ? sums[tid - off] : 0;
        __syncthreads();
        sums[tid] += v;
        __syncthreads();
    }
    int run = (tid == 0) ? 0 : sums[tid - 1];
    for (int i = 0; i < per; i++) {
        int idx = base + i;
        if (idx < N_NODES) { row_start[idx] = run; run += counts[idx]; }
    }
    if (tid == 1023) row_start[N_NODES] = run;  // = ETOT
}

__global__ void scatter_kernel(const int* __restrict__ ei, const int* __restrict__ row_start,
                               int* __restrict__ cursor, int* __restrict__ csr_src) {
    int e = blockIdx.x * blockDim.x + threadIdx.x;
    if (e >= ETOT) return;
    int s, d;
    if (e < N_EDGES) { s = ei[e]; d = ei[N_EDGES + e]; }
    else             { s = e - N_EDGES; d = s; }
    int pos = atomicAdd(&cursor[d], 1);
    csr_src[row_start[d] + pos] = s;
}

// ---------------------------------------------------------------------------
// Layer 1: xw1 = feats @ W1  [N,320], plus attention scores s_src/s_dst [N,10]
// block: 320 threads (thread t = h*32+f), 8 nodes per block
// ---------------------------------------------------------------------------
__global__ void gemm1_kernel(const float* __restrict__ x, const float* __restrict__ W1,
                             const float* __restrict__ a_src, const float* __restrict__ a_dst,
                             float* __restrict__ xw1, float* __restrict__ s_src,
                             float* __restrict__ s_dst) {
    __shared__ float w[F_IN * C1];   // 40 KB
    __shared__ float xr[8][F_IN];
    int t = threadIdx.x;
    for (int i = t; i < F_IN * C1; i += C1) w[i] = W1[i];
    int n0 = blockIdx.x * 8;
    for (int i = t; i < 8 * F_IN; i += C1) {
        int r = i >> 5, c = i & 31;
        xr[r][c] = x[(n0 + r) * F_IN + c];
    }
    __syncthreads();
    int h = t >> 5, f = t & 31;
    float as = a_src[t];   // a_src[h][f]
    float ad = a_dst[t];
    for (int r = 0; r < 8; r++) {
        int n = n0 + r;
        float acc = 0.f;
#pragma unroll
        for (int k = 0; k < F_IN; k++) acc += xr[r][k] * w[k * C1 + t];
        xw1[n * C1 + t] = acc;
        // reduce over f within each 32-lane half (head)
        float vs = acc * as, vd = acc * ad;
#pragma unroll
        for (int off = 16; off >= 1; off >>= 1) {
            vs += __shfl_xor(vs, off);
            vd += __shfl_xor(vd, off);
        }
        if (f == 0) { s_src[n * HEADS + h] = vs; s_dst[n * HEADS + h] = vd; }
    }
}

// ---------------------------------------------------------------------------
// Layer 1 aggregation: two-phase softmax per node
//   phase A: edge weights p_i (all heads) into LDS  — touches only score arrays
//   phase B: pure gather-FMA over edges, unrolled x4 for memory-level parallelism
// block: 320 threads (t = h*32+f), one node per block
// ---------------------------------------------------------------------------
__global__ __launch_bounds__(320) void agg1_kernel(
        const float* __restrict__ xw1, const float* __restrict__ s_src,
        const float* __restrict__ s_dst, const int* __restrict__ row_start,
        const int* __restrict__ csr_src, const float* __restrict__ b1,
        float* __restrict__ h1) {
    __shared__ int   sh_src[MAXDEG];
    __shared__ float sh_p[MAXDEG * HEADS];
    int n = blockIdx.x;
    int t = threadIdx.x;
    int h = t >> 5, lane32 = t & 31;
    int beg = row_start[n], deg = row_start[n + 1] - beg;
    float sd = s_dst[n * HEADS + h];
    float m = -1e30f, l = 0.f, acc = 0.f;

    for (int c0 = 0; c0 < deg; c0 += MAXDEG) {
        int degc = min(deg - c0, MAXDEG);
        if (t < degc) sh_src[t] = csr_src[beg + c0 + t];
        __syncthreads();

        // ---- phase A: scores for this head (32 lanes handle all edges) ----
        float earr[MAXDEG / 32];
        float mx = -1e30f;
        for (int i = lane32, j = 0; i < degc; i += 32, j++) {
            int s = sh_src[i];
            float e = s_src[s * HEADS + h] + sd;
            e = (e >= 0.f) ? e : 0.2f * e;           // leaky_relu(0.2)
            earr[j] = e;
            mx = fmaxf(mx, e);
        }
#pragma unroll
        for (int off = 16; off >= 1; off >>= 1) mx = fmaxf(mx, __shfl_xor(mx, off));
        float mn = fmaxf(m, mx);
        float sc = __expf(m - mn);
        float lsum = 0.f;
        for (int i = lane32, j = 0; i < degc; i += 32, j++) {
            float p = __expf(earr[j] - mn);
            sh_p[i * HEADS + h] = p;
            lsum += p;
        }
#pragma unroll
        for (int off = 16; off >= 1; off >>= 1) lsum += __shfl_xor(lsum, off);
        l = l * sc + lsum;
        m = mn;
        __syncthreads();

        // ---- phase B: gather-FMA, 4 gathers in flight ----
        float partial = 0.f;
        int i = 0;
        for (; i + 4 <= degc; i += 4) {
            int s0 = sh_src[i + 0], s1 = sh_src[i + 1];
            int s2 = sh_src[i + 2], s3 = sh_src[i + 3];
            float p0 = sh_p[(i + 0) * HEADS + h], p1 = sh_p[(i + 1) * HEADS + h];
            float p2 = sh_p[(i + 2) * HEADS + h], p3 = sh_p[(i + 3) * HEADS + h];
            float v0 = xw1[(size_t)s0 * C1 + t];
            float v1 = xw1[(size_t)s1 * C1 + t];
            float v2 = xw1[(size_t)s2 * C1 + t];
            float v3 = xw1[(size_t)s3 * C1 + t];
            partial += p0 * v0;
            partial += p1 * v1;
            partial += p2 * v2;
            partial += p3 * v3;
        }
        for (; i < degc; i++)
            partial += sh_p[i * HEADS + h] * xw1[(size_t)sh_src[i] * C1 + t];
        acc = acc * sc + partial;
        __syncthreads();
    }

    float o = acc / fmaxf(l, 1e-16f) + b1[t];
    o = (o > 0.f) ? o : (__expf(o) - 1.f);           // ELU
    h1[n * C1 + t] = o;
}

// ---------------------------------------------------------------------------
// Layer 2 GEMM: xw2 = h1 @ W2  [N,128], plus scalar scores s2_src/s2_dst [N]
// ---------------------------------------------------------------------------
__global__ void gemm2_kernel(const float* __restrict__ h1, const float* __restrict__ W2,
                             const float* __restrict__ a_src, const float* __restrict__ a_dst,
                             float* __restrict__ xw2, float* __restrict__ s_src2,
                             float* __restrict__ s_dst2) {
    __shared__ float A[16 * C1];     // 20 KB
    __shared__ float redS[2][16];
    __shared__ float redD[2][16];
    int t = threadIdx.x;
    int n0 = blockIdx.x * 16;
    for (int i = t; i < 16 * C1; i += 128) A[i] = h1[n0 * C1 + i];
    __syncthreads();
    float acc[16];
#pragma unroll
    for (int r = 0; r < 16; r++) acc[r] = 0.f;
    for (int k = 0; k < C1; k++) {
        float b = W2[k * C2 + t];
#pragma unroll
        for (int r = 0; r < 16; r++) acc[r] += A[r * C1 + k] * b;
    }
    float as = a_src[t], ad = a_dst[t];
    int lane = t & 63, wave = t >> 6;
    for (int r = 0; r < 16; r++) {
        xw2[(n0 + r) * C2 + t] = acc[r];
        float vs = acc[r] * as, vd = acc[r] * ad;
#pragma unroll
        for (int off = 32; off >= 1; off >>= 1) {
            vs += __shfl_xor(vs, off);
            vd += __shfl_xor(vd, off);
        }
        if (lane == 0) { redS[wave][r] = vs; redD[wave][r] = vd; }
    }
    __syncthreads();
    if (t < 16)       s_src2[n0 + t]      = redS[0][t] + redS[1][t];
    else if (t < 32)  s_dst2[n0 + t - 16] = redD[0][t - 16] + redD[1][t - 16];
}

// ---------------------------------------------------------------------------
// Layer 2 aggregation (H=1), two-phase + ReLU
// ---------------------------------------------------------------------------
__global__ __launch_bounds__(128) void agg2_kernel(
        const float* __restrict__ xw2, const float* __restrict__ s_src2,
        const float* __restrict__ s_dst2, const int* __restrict__ row_start,
        const int* __restrict__ csr_src, const float* __restrict__ b2,
        float* __restrict__ x2) {
    __shared__ int   sh_src[MAXDEG];
    __shared__ float sh_p[MAXDEG];
    __shared__ float sh_bc[2];
    int n = blockIdx.x;
    int t = threadIdx.x;   // 128
    int beg = row_start[n], deg = row_start[n + 1] - beg;
    float sd = s_dst2[n];
    float m = -1e30f, l = 0.f, acc = 0.f;

    for (int c0 = 0; c0 < deg; c0 += MAXDEG) {
        int degc = min(deg - c0, MAXDEG);
        if (t < degc) sh_src[t] = csr_src[beg + c0 + t];
        __syncthreads();

        float scv;
        if (t < 64) {   // wave 0 computes all edge weights
            float e0 = -1e30f, e1 = -1e30f;
            if (t < degc) {
                float e = s_src2[sh_src[t]] + sd;
                e0 = (e >= 0.f) ? e : 0.2f * e;
            }
            if (t + 64 < degc) {
                float e = s_src2[sh_src[t + 64]] + sd;
                e1 = (e >= 0.f) ? e : 0.2f * e;
            }
            float mx = fmaxf(e0, e1);
#pragma unroll
            for (int off = 32; off >= 1; off >>= 1) mx = fmaxf(mx, __shfl_xor(mx, off));
            float mn = fmaxf(m, mx);
            scv = __expf(m - mn);
            float p0 = (t < degc)      ? __expf(e0 - mn) : 0.f;
            float p1 = (t + 64 < degc) ? __expf(e1 - mn) : 0.f;
            if (t < degc)      sh_p[t]      = p0;
            if (t + 64 < degc) sh_p[t + 64] = p1;
            float lsum = p0 + p1;
#pragma unroll
            for (int off = 32; off >= 1; off >>= 1) lsum += __shfl_xor(lsum, off);
            l = l * scv + lsum;
            m = mn;
            if (t == 0) sh_bc[0] = scv;
        }
        __syncthreads();
        if (t >= 64) scv = sh_bc[0];

        float partial = 0.f;
        int i = 0;
        for (; i + 4 <= degc; i += 4) {
            int s0 = sh_src[i + 0], s1 = sh_src[i + 1];
            int s2 = sh_src[i + 2], s3 = sh_src[i + 3];
            float p0 = sh_p[i + 0], p1 = sh_p[i + 1];
            float p2 = sh_p[i + 2], p3 = sh_p[i + 3];
            float v0 = xw2[(size_t)s0 * C2 + t];
            float v1 = xw2[(size_t)s1 * C2 + t];
            float v2 = xw2[(size_t)s2 * C2 + t];
            float v3 = xw2[(size_t)s3 * C2 + t];
            partial += p0 * v0;
            partial += p1 * v1;
            partial += p2 * v2;
            partial += p3 * v3;
        }
        for (; i < degc; i++)
            partial += sh_p[i] * xw2[(size_t)sh_src[i] * C2 + t];
        acc = acc * scv + partial;
        __syncthreads();
    }

    if (t == 0) sh_bc[1] = l;
    __syncthreads();
    l = sh_bc[1];
    float o = acc / fmaxf(l, 1e-16f) + b2[t];
    x2[n * C2 + t] = fmaxf(o, 0.f);              // ReLU
}

// ---------------------------------------------------------------------------
// Main output: relu(x2 @ fc_w + fc_b)  ([B,PER,128] == [N,128], identity split)
// ---------------------------------------------------------------------------
__global__ void fc_main_kernel(const float* __restrict__ x2, const float* __restrict__ fc_w,
                               const float* __restrict__ fc_b, float* __restrict__ out) {
    __shared__ float A[16 * C2];     // 8 KB
    int t = threadIdx.x;
    int n0 = blockIdx.x * 16;
    for (int i = t; i < 16 * C2; i += 128) A[i] = x2[n0 * C2 + i];
    __syncthreads();
    float acc[16];
#pragma unroll
    for (int r = 0; r < 16; r++) acc[r] = 0.f;
    for (int k = 0; k < C2; k++) {
        float b = fc_w[k * C2 + t];
#pragma unroll
        for (int r = 0; r < 16; r++) acc[r] += A[r * C2 + k] * b;
    }
    float bb = fc_b[t];
    for (int r = 0; r < 16; r++)
        out[(n0 + r) * C2 + t] = fmaxf(acc[r] + bb, 0.f);
}

// ---------------------------------------------------------------------------
// Pooling: per-graph max over 200 nodes, then relu(pooled @ fc_w + fc_b)
// ---------------------------------------------------------------------------
__global__ void pool_kernel(const float* __restrict__ x2, float* __restrict__ pooled) {
    int g = blockIdx.x, t = threadIdx.x;   // 128
    float mx = -1e30f;
    for (int i = 0; i < PER; i++)
        mx = fmaxf(mx, x2[(g * PER + i) * C2 + t]);
    pooled[g * C2 + t] = mx;
}

__global__ void fc_pool_kernel(const float* __restrict__ pooled, const float* __restrict__ fc_w,
                               const float* __restrict__ fc_b, float* __restrict__ outp) {
    __shared__ float A[C2];
    int g = blockIdx.x, t = threadIdx.x;
    A[t] = pooled[g * C2 + t];
    __syncthreads();
    float acc = 0.f;
    for (int k = 0; k < C2; k++) acc += A[k] * fc_w[k * C2 + t];
    outp[g * C2 + t] = fmaxf(acc + fc_b[t], 0.f);
}

// ---------------------------------------------------------------------------
extern "C" void kernel_launch(void* const* d_in, const int* in_sizes, int n_in,
                              void* d_out, int out_size, void* d_ws, size_t ws_size,
                              hipStream_t stream) {
    const float* feats = (const float*)d_in[0];
    const int*   ei    = (const int*)d_in[1];
    // d_in[2] graph_id, d_in[3] batch_num_nodes: layout is uniform -> unused
    const float* W1  = (const float*)d_in[4];
    const float* a1s = (const float*)d_in[5];
    const float* a1d = (const float*)d_in[6];
    const float* b1  = (const float*)d_in[7];
    const float* W2  = (const float*)d_in[8];
    const float* a2s = (const float*)d_in[9];
    const float* a2d = (const float*)d_in[10];
    const float* b2  = (const float*)d_in[11];
    const float* fcw = (const float*)d_in[12];
    const float* fcb = (const float*)d_in[13];

    float* out_main = (float*)d_out;                        // [20000,128]
    float* out_pool = (float*)d_out + (size_t)N_NODES * C2; // [100,128]

    char* p = (char*)d_ws;
    auto alloc = [&](size_t bytes) {
        char* r = p;
        p += (bytes + 255) & ~(size_t)255;
        return r;
    };
    float* xw1    = (float*)alloc(sizeof(float) * N_NODES * C1);
    float* h1     = (float*)alloc(sizeof(float) * N_NODES * C1);
    float* s1s    = (float*)alloc(sizeof(float) * N_NODES * HEADS);
    float* s1d    = (float*)alloc(sizeof(float) * N_NODES * HEADS);
    float* xw2    = (float*)alloc(sizeof(float) * N_NODES * C2);
    float* s2s    = (float*)alloc(sizeof(float) * N_NODES);
    float* s2d    = (float*)alloc(sizeof(float) * N_NODES);
    float* x2     = (float*)alloc(sizeof(float) * N_NODES * C2);
    float* pooled = (float*)alloc(sizeof(float) * NB * C2);
    int* counts   = (int*)alloc(sizeof(int) * N_NODES * 2);  // counts + cursor
    int* cursor   = counts + N_NODES;
    int* row_start = (int*)alloc(sizeof(int) * (N_NODES + 1));
    int* csr_src  = (int*)alloc(sizeof(int) * ETOT);

    // zero histogram + scatter cursors (ws is poisoned before every launch)
    hipMemsetAsync(counts, 0, sizeof(int) * N_NODES * 2, stream);

    hist_kernel<<<(ETOT + 255) / 256, 256, 0, stream>>>(ei, counts);
    scan_kernel<<<1, 1024, 0, stream>>>(counts, row_start);
    scatter_kernel<<<(ETOT + 255) / 256, 256, 0, stream>>>(ei, row_start, cursor, csr_src);

    gemm1_kernel<<<N_NODES / 8, C1, 0, stream>>>(feats, W1, a1s, a1d, xw1, s1s, s1d);
    agg1_kernel<<<N_NODES, C1, 0, stream>>>(xw1, s1s, s1d, row_start, csr_src, b1, h1);
    gemm2_kernel<<<N_NODES / 16, C2, 0, stream>>>(h1, W2, a2s, a2d, xw2, s2s, s2d);
    agg2_kernel<<<N_NODES, C2, 0, stream>>>(xw2, s2s, s2d, row_start, csr_src, b2, x2);
    fc_main_kernel<<<N_NODES / 16, C2, 0, stream>>>(x2, fcw, fcb, out_main);
    pool_kernel<<<NB, C2, 0, stream>>>(x2, pooled);
    fc_pool_kernel<<<NB, C2, 0, stream>>>(pooled, fcw, fcb, out_pool);
}

// Round 3
// 342.783 us; speedup vs baseline: 1.3434x; 1.1614x over previous
//
#include <hip/hip_runtime.h>

// Problem constants (fixed by the reference)
#define N_NODES 20000
#define N_EDGES 320000
#define ETOT    (N_EDGES + N_NODES)   // edges + self-loops = 340000
#define HEADS   10
#define F_IN    32
#define C1      (HEADS * F_IN)        // 320
#define C2      128
#define NB      100
#define PER     200
#define MAXDEG  128                   // chunk size for per-node edge lists
#define PSTRIDE 11                    // sh_p stride: gcd(11,32)=1 -> conflict-free

typedef __attribute__((ext_vector_type(8))) short bf16x8;   // MFMA A/B frag (4 VGPRs)
typedef __attribute__((ext_vector_type(4))) float floatx4;  // MFMA C/D frag

static __device__ __forceinline__ unsigned short f2bf(float f) {
    unsigned int u = __float_as_uint(f);
    unsigned int r = (u + 0x7fffu + ((u >> 16) & 1u)) >> 16;   // RNE
    return (unsigned short)r;
}
static __device__ __forceinline__ float bf2f(unsigned short b) {
    return __uint_as_float(((unsigned int)b) << 16);
}

// ---------------------------------------------------------------------------
// CSR-by-destination construction (shared by both GAT layers)
// ---------------------------------------------------------------------------
__global__ void hist_kernel(const int* __restrict__ ei, int* __restrict__ counts) {
    int e = blockIdx.x * blockDim.x + threadIdx.x;
    if (e >= ETOT) return;
    int d = (e < N_EDGES) ? ei[N_EDGES + e] : (e - N_EDGES);
    atomicAdd(&counts[d], 1);
}

__global__ void scan_kernel(const int* __restrict__ counts, int* __restrict__ row_start) {
    __shared__ int sums[1024];
    int tid = threadIdx.x;
    const int per = (N_NODES + 1023) / 1024;  // 20
    int base = tid * per;
    int s = 0;
    for (int i = 0; i < per; i++) {
        int idx = base + i;
        if (idx < N_NODES) s += counts[idx];
    }
    sums[tid] = s;
    __syncthreads();
    for (int off = 1; off < 1024; off <<= 1) {
        int v = (tid >= off) ? sums[tid - off] : 0;
        __syncthreads();
        sums[tid] += v;
        __syncthreads();
    }
    int run = (tid == 0) ? 0 : sums[tid - 1];
    for (int i = 0; i < per; i++) {
        int idx = base + i;
        if (idx < N_NODES) { row_start[idx] = run; run += counts[idx]; }
    }
    if (tid == 1023) row_start[N_NODES] = run;  // = ETOT
}

__global__ void scatter_kernel(const int* __restrict__ ei, const int* __restrict__ row_start,
                               int* __restrict__ cursor, int* __restrict__ csr_src) {
    int e = blockIdx.x * blockDim.x + threadIdx.x;
    if (e >= ETOT) return;
    int s, d;
    if (e < N_EDGES) { s = ei[e]; d = ei[N_EDGES + e]; }
    else             { s = e - N_EDGES; d = s; }
    int pos = atomicAdd(&cursor[d], 1);
    csr_src[row_start[d] + pos] = s;
}

// ---------------------------------------------------------------------------
// W2 -> MFMA B-fragment layout, bf16.
// Frag layout (16x16x32): lane holds B[k = quad*8 + j][n = lane&15], j=0..7
// W2p[((kb*8 + ct)*64 + lane)*8 + j] = bf16(W2[(kb*32 + quad*8 + j)*128 + ct*16 + (lane&15)])
// ---------------------------------------------------------------------------
__global__ void w2prep_kernel(const float* __restrict__ W2, unsigned short* __restrict__ W2p) {
    int o = blockIdx.x * blockDim.x + threadIdx.x;   // 40960 total
    if (o >= C1 * C2) return;
    int j    = o & 7;
    int lane = (o >> 3) & 63;
    int ct   = (o >> 9) & 7;
    int kb   = o >> 12;
    int k = kb * 32 + (lane >> 4) * 8 + j;
    int n = ct * 16 + (lane & 15);
    W2p[o] = f2bf(W2[k * C2 + n]);
}

// ---------------------------------------------------------------------------
// Layer 1: xw1 = feats @ W1 (stored bf16), attention scores s_src/s_dst fp32
// block: 320 threads (t = h*32+f), 8 nodes per block
// ---------------------------------------------------------------------------
__global__ void gemm1_kernel(const float* __restrict__ x, const float* __restrict__ W1,
                             const float* __restrict__ a_src, const float* __restrict__ a_dst,
                             unsigned short* __restrict__ xw1b, float* __restrict__ s_src,
                             float* __restrict__ s_dst) {
    __shared__ float w[F_IN * C1];   // 40 KB
    __shared__ float xr[8][F_IN];
    int t = threadIdx.x;
    for (int i = t; i < F_IN * C1; i += C1) w[i] = W1[i];
    int n0 = blockIdx.x * 8;
    for (int i = t; i < 8 * F_IN; i += C1) {
        int r = i >> 5, c = i & 31;
        xr[r][c] = x[(n0 + r) * F_IN + c];
    }
    __syncthreads();
    int h = t >> 5, f = t & 31;
    float as = a_src[t];
    float ad = a_dst[t];
    for (int r = 0; r < 8; r++) {
        int n = n0 + r;
        float acc = 0.f;
#pragma unroll
        for (int k = 0; k < F_IN; k++) acc += xr[r][k] * w[k * C1 + t];
        xw1b[(size_t)n * C1 + t] = f2bf(acc);
        float vs = acc * as, vd = acc * ad;
#pragma unroll
        for (int off = 16; off >= 1; off >>= 1) {
            vs += __shfl_xor(vs, off);
            vd += __shfl_xor(vd, off);
        }
        if (f == 0) { s_src[n * HEADS + h] = vs; s_dst[n * HEADS + h] = vd; }
    }
}

// ---------------------------------------------------------------------------
// Layer 1 aggregation: two-phase softmax, bf16 value gather (unroll x8) + ELU
// block: 320 threads (t = h*32+f), one node per block; h1 stored bf16
// ---------------------------------------------------------------------------
__global__ __launch_bounds__(320) void agg1_kernel(
        const unsigned short* __restrict__ xw1b, const float* __restrict__ s_src,
        const float* __restrict__ s_dst, const int* __restrict__ row_start,
        const int* __restrict__ csr_src, const float* __restrict__ b1,
        unsigned short* __restrict__ h1b) {
    __shared__ int   sh_src[MAXDEG];
    __shared__ float sh_p[MAXDEG * PSTRIDE];
    int n = blockIdx.x;
    int t = threadIdx.x;
    int h = t >> 5, lane32 = t & 31;
    int beg = row_start[n], deg = row_start[n + 1] - beg;
    float sd = s_dst[n * HEADS + h];
    float m = -1e30f, l = 0.f, acc = 0.f;

    for (int c0 = 0; c0 < deg; c0 += MAXDEG) {
        int degc = min(deg - c0, MAXDEG);
        if (t < degc) sh_src[t] = csr_src[beg + c0 + t];
        __syncthreads();

        // ---- phase A: this head's edge scores (32 lanes cover all edges) ----
        float earr[MAXDEG / 32];
        float mx = -1e30f;
        for (int i = lane32, j = 0; i < degc; i += 32, j++) {
            int s = sh_src[i];
            float e = s_src[s * HEADS + h] + sd;
            e = (e >= 0.f) ? e : 0.2f * e;           // leaky_relu(0.2)
            earr[j] = e;
            mx = fmaxf(mx, e);
        }
#pragma unroll
        for (int off = 16; off >= 1; off >>= 1) mx = fmaxf(mx, __shfl_xor(mx, off));
        float mn = fmaxf(m, mx);
        float sc = __expf(m - mn);
        float lsum = 0.f;
        for (int i = lane32, j = 0; i < degc; i += 32, j++) {
            float p = __expf(earr[j] - mn);
            sh_p[i * PSTRIDE + h] = p;
            lsum += p;
        }
#pragma unroll
        for (int off = 16; off >= 1; off >>= 1) lsum += __shfl_xor(lsum, off);
        l = l * sc + lsum;
        m = mn;
        __syncthreads();

        // ---- phase B: bf16 gather-FMA, 8 gathers in flight ----
        float partial = 0.f;
        int i = 0;
        for (; i + 8 <= degc; i += 8) {
            int   s0 = sh_src[i + 0], s1 = sh_src[i + 1], s2 = sh_src[i + 2], s3 = sh_src[i + 3];
            int   s4 = sh_src[i + 4], s5 = sh_src[i + 5], s6 = sh_src[i + 6], s7 = sh_src[i + 7];
            float v0 = bf2f(xw1b[(size_t)s0 * C1 + t]);
            float v1 = bf2f(xw1b[(size_t)s1 * C1 + t]);
            float v2 = bf2f(xw1b[(size_t)s2 * C1 + t]);
            float v3 = bf2f(xw1b[(size_t)s3 * C1 + t]);
            float v4 = bf2f(xw1b[(size_t)s4 * C1 + t]);
            float v5 = bf2f(xw1b[(size_t)s5 * C1 + t]);
            float v6 = bf2f(xw1b[(size_t)s6 * C1 + t]);
            float v7 = bf2f(xw1b[(size_t)s7 * C1 + t]);
            partial += sh_p[(i + 0) * PSTRIDE + h] * v0;
            partial += sh_p[(i + 1) * PSTRIDE + h] * v1;
            partial += sh_p[(i + 2) * PSTRIDE + h] * v2;
            partial += sh_p[(i + 3) * PSTRIDE + h] * v3;
            partial += sh_p[(i + 4) * PSTRIDE + h] * v4;
            partial += sh_p[(i + 5) * PSTRIDE + h] * v5;
            partial += sh_p[(i + 6) * PSTRIDE + h] * v6;
            partial += sh_p[(i + 7) * PSTRIDE + h] * v7;
        }
        for (; i < degc; i++)
            partial += sh_p[i * PSTRIDE + h] * bf2f(xw1b[(size_t)sh_src[i] * C1 + t]);
        acc = acc * sc + partial;
        __syncthreads();
    }

    float o = acc / fmaxf(l, 1e-16f) + b1[t];
    o = (o > 0.f) ? o : (__expf(o) - 1.f);           // ELU
    h1b[(size_t)n * C1 + t] = f2bf(o);
}

// ---------------------------------------------------------------------------
// Layer 2 GEMM via MFMA bf16: xw2 = h1 @ W2 (fp32 out) + fused s2 scores
// block: 256 threads = 4 waves; wave handles one 16-row tile x 128 cols
// ---------------------------------------------------------------------------
__global__ __launch_bounds__(256) void gemm2_mfma_kernel(
        const unsigned short* __restrict__ h1b, const unsigned short* __restrict__ W2p,
        const float* __restrict__ a_src, const float* __restrict__ a_dst,
        float* __restrict__ xw2, float* __restrict__ s_src2, float* __restrict__ s_dst2) {
    int wave = threadIdx.x >> 6;
    int lane = threadIdx.x & 63;
    int tile = blockIdx.x * 4 + wave;            // 16-row tile index
    if (tile >= N_NODES / 16) return;            // 1250 tiles
    int quad = lane >> 4, col = lane & 15;
    int row0 = tile * 16;

    floatx4 acc[8];
#pragma unroll
    for (int ct = 0; ct < 8; ct++) acc[ct] = (floatx4){0.f, 0.f, 0.f, 0.f};

    const bf16x8* pb = (const bf16x8*)W2p;       // [(kb*8+ct)*64 + lane]
    int m = row0 + col;                          // A-frag row for this lane
#pragma unroll
    for (int kb = 0; kb < 10; kb++) {
        bf16x8 a = *(const bf16x8*)(h1b + (size_t)m * C1 + kb * 32 + quad * 8);
#pragma unroll
        for (int ct = 0; ct < 8; ct++) {
            bf16x8 b = pb[(kb * 8 + ct) * 64 + lane];
            acc[ct] = __builtin_amdgcn_mfma_f32_16x16x32_bf16(a, b, acc[ct], 0, 0, 0);
        }
    }

    // epilogue: store xw2 fp32 + fused s2 scores
    float asv[8], adv[8];
#pragma unroll
    for (int ct = 0; ct < 8; ct++) { asv[ct] = a_src[ct * 16 + col]; adv[ct] = a_dst[ct * 16 + col]; }

#pragma unroll
    for (int reg = 0; reg < 4; reg++) {
        int row = row0 + quad * 4 + reg;
        float vs = 0.f, vd = 0.f;
#pragma unroll
        for (int ct = 0; ct < 8; ct++) {
            float v = acc[ct][reg];
            xw2[(size_t)row * C2 + ct * 16 + col] = v;
            vs += v * asv[ct];
            vd += v * adv[ct];
        }
        // reduce over the 16 lanes sharing this quad (cols)
#pragma unroll
        for (int off = 8; off >= 1; off >>= 1) {
            vs += __shfl_xor(vs, off);
            vd += __shfl_xor(vd, off);
        }
        if (col == 0) { s_src2[row] = vs; s_dst2[row] = vd; }
    }
}

// ---------------------------------------------------------------------------
// Layer 2 aggregation (H=1), two-phase, fp32 gather (unroll x8) + ReLU
// ---------------------------------------------------------------------------
__global__ __launch_bounds__(128) void agg2_kernel(
        const float* __restrict__ xw2, const float* __restrict__ s_src2,
        const float* __restrict__ s_dst2, const int* __restrict__ row_start,
        const int* __restrict__ csr_src, const float* __restrict__ b2,
        float* __restrict__ x2) {
    __shared__ int   sh_src[MAXDEG];
    __shared__ float sh_p[MAXDEG];
    __shared__ float sh_bc[2];
    int n = blockIdx.x;
    int t = threadIdx.x;   // 128
    int beg = row_start[n], deg = row_start[n + 1] - beg;
    float sd = s_dst2[n];
    float m = -1e30f, l = 0.f, acc = 0.f;

    for (int c0 = 0; c0 < deg; c0 += MAXDEG) {
        int degc = min(deg - c0, MAXDEG);
        if (t < degc) sh_src[t] = csr_src[beg + c0 + t];
        __syncthreads();

        float scv;
        if (t < 64) {   // wave 0 computes all edge weights
            float e0 = -1e30f, e1 = -1e30f;
            if (t < degc) {
                float e = s_src2[sh_src[t]] + sd;
                e0 = (e >= 0.f) ? e : 0.2f * e;
            }
            if (t + 64 < degc) {
                float e = s_src2[sh_src[t + 64]] + sd;
                e1 = (e >= 0.f) ? e : 0.2f * e;
            }
            float mx = fmaxf(e0, e1);
#pragma unroll
            for (int off = 32; off >= 1; off >>= 1) mx = fmaxf(mx, __shfl_xor(mx, off));
            float mn = fmaxf(m, mx);
            scv = __expf(m - mn);
            float p0 = (t < degc)      ? __expf(e0 - mn) : 0.f;
            float p1 = (t + 64 < degc) ? __expf(e1 - mn) : 0.f;
            if (t < degc)      sh_p[t]      = p0;
            if (t + 64 < degc) sh_p[t + 64] = p1;
            float lsum = p0 + p1;
#pragma unroll
            for (int off = 32; off >= 1; off >>= 1) lsum += __shfl_xor(lsum, off);
            l = l * scv + lsum;
            m = mn;
            if (t == 0) sh_bc[0] = scv;
        }
        __syncthreads();
        if (t >= 64) scv = sh_bc[0];

        float partial = 0.f;
        int i = 0;
        for (; i + 8 <= degc; i += 8) {
            int s0 = sh_src[i + 0], s1 = sh_src[i + 1], s2 = sh_src[i + 2], s3 = sh_src[i + 3];
            int s4 = sh_src[i + 4], s5 = sh_src[i + 5], s6 = sh_src[i + 6], s7 = sh_src[i + 7];
            float v0 = xw2[(size_t)s0 * C2 + t];
            float v1 = xw2[(size_t)s1 * C2 + t];
            float v2 = xw2[(size_t)s2 * C2 + t];
            float v3 = xw2[(size_t)s3 * C2 + t];
            float v4 = xw2[(size_t)s4 * C2 + t];
            float v5 = xw2[(size_t)s5 * C2 + t];
            float v6 = xw2[(size_t)s6 * C2 + t];
            float v7 = xw2[(size_t)s7 * C2 + t];
            partial += sh_p[i + 0] * v0;
            partial += sh_p[i + 1] * v1;
            partial += sh_p[i + 2] * v2;
            partial += sh_p[i + 3] * v3;
            partial += sh_p[i + 4] * v4;
            partial += sh_p[i + 5] * v5;
            partial += sh_p[i + 6] * v6;
            partial += sh_p[i + 7] * v7;
        }
        for (; i < degc; i++)
            partial += sh_p[i] * xw2[(size_t)sh_src[i] * C2 + t];
        acc = acc * scv + partial;
        __syncthreads();
    }

    if (t == 0) sh_bc[1] = l;
    __syncthreads();
    l = sh_bc[1];
    float o = acc / fmaxf(l, 1e-16f) + b2[t];
    x2[(size_t)n * C2 + t] = fmaxf(o, 0.f);      // ReLU
}

// ---------------------------------------------------------------------------
// Main output: relu(x2 @ fc_w + fc_b)  (identity split) — float4 LDS broadcasts
// ---------------------------------------------------------------------------
__global__ void fc_main_kernel(const float* __restrict__ x2, const float* __restrict__ fc_w,
                               const float* __restrict__ fc_b, float* __restrict__ out) {
    __shared__ __align__(16) float A[16 * C2];   // 8 KB
    int t = threadIdx.x;
    int n0 = blockIdx.x * 16;
    for (int i = t; i < 16 * C2; i += 128) A[i] = x2[(size_t)n0 * C2 + i];
    __syncthreads();
    float acc[16];
#pragma unroll
    for (int r = 0; r < 16; r++) acc[r] = 0.f;
    for (int k = 0; k < C2; k += 4) {
        float b0 = fc_w[(k + 0) * C2 + t];
        float b1 = fc_w[(k + 1) * C2 + t];
        float b2 = fc_w[(k + 2) * C2 + t];
        float b3 = fc_w[(k + 3) * C2 + t];
#pragma unroll
        for (int r = 0; r < 16; r++) {
            float4 a4 = *(const float4*)&A[r * C2 + k];
            acc[r] += a4.x * b0 + a4.y * b1 + a4.z * b2 + a4.w * b3;
        }
    }
    float bb = fc_b[t];
    for (int r = 0; r < 16; r++)
        out[(size_t)(n0 + r) * C2 + t] = fmaxf(acc[r] + bb, 0.f);
}

// ---------------------------------------------------------------------------
// Pooling: per-graph max over 200 nodes, then relu(pooled @ fc_w + fc_b)
// ---------------------------------------------------------------------------
__global__ void pool_kernel(const float* __restrict__ x2, float* __restrict__ pooled) {
    int g = blockIdx.x, t = threadIdx.x;   // 128
    float mx = -1e30f;
    for (int i = 0; i < PER; i++)
        mx = fmaxf(mx, x2[(size_t)(g * PER + i) * C2 + t]);
    pooled[g * C2 + t] = mx;
}

__global__ void fc_pool_kernel(const float* __restrict__ pooled, const float* __restrict__ fc_w,
                               const float* __restrict__ fc_b, float* __restrict__ outp) {
    __shared__ float A[C2];
    int g = blockIdx.x, t = threadIdx.x;
    A[t] = pooled[g * C2 + t];
    __syncthreads();
    float acc = 0.f;
    for (int k = 0; k < C2; k++) acc += A[k] * fc_w[k * C2 + t];
    outp[g * C2 + t] = fmaxf(acc + fc_b[t], 0.f);
}

// ---------------------------------------------------------------------------
extern "C" void kernel_launch(void* const* d_in, const int* in_sizes, int n_in,
                              void* d_out, int out_size, void* d_ws, size_t ws_size,
                              hipStream_t stream) {
    const float* feats = (const float*)d_in[0];
    const int*   ei    = (const int*)d_in[1];
    const float* W1  = (const float*)d_in[4];
    const float* a1s = (const float*)d_in[5];
    const float* a1d = (const float*)d_in[6];
    const float* b1  = (const float*)d_in[7];
    const float* W2  = (const float*)d_in[8];
    const float* a2s = (const float*)d_in[9];
    const float* a2d = (const float*)d_in[10];
    const float* b2  = (const float*)d_in[11];
    const float* fcw = (const float*)d_in[12];
    const float* fcb = (const float*)d_in[13];

    float* out_main = (float*)d_out;                        // [20000,128]
    float* out_pool = (float*)d_out + (size_t)N_NODES * C2; // [100,128]

    char* p = (char*)d_ws;
    auto alloc = [&](size_t bytes) {
        char* r = p;
        p += (bytes + 255) & ~(size_t)255;
        return r;
    };
    unsigned short* xw1b = (unsigned short*)alloc(sizeof(short) * (size_t)N_NODES * C1);
    unsigned short* h1b  = (unsigned short*)alloc(sizeof(short) * (size_t)N_NODES * C1);
    unsigned short* W2p  = (unsigned short*)alloc(sizeof(short) * C1 * C2);
    float* s1s    = (float*)alloc(sizeof(float) * N_NODES * HEADS);
    float* s1d    = (float*)alloc(sizeof(float) * N_NODES * HEADS);
    float* xw2    = (float*)alloc(sizeof(float) * (size_t)N_NODES * C2);
    float* s2s    = (float*)alloc(sizeof(float) * N_NODES);
    float* s2d    = (float*)alloc(sizeof(float) * N_NODES);
    float* x2     = (float*)alloc(sizeof(float) * (size_t)N_NODES * C2);
    float* pooled = (float*)alloc(sizeof(float) * NB * C2);
    int* counts   = (int*)alloc(sizeof(int) * N_NODES * 2);  // counts + cursor
    int* cursor   = counts + N_NODES;
    int* row_start = (int*)alloc(sizeof(int) * (N_NODES + 1));
    int* csr_src  = (int*)alloc(sizeof(int) * ETOT);

    hipMemsetAsync(counts, 0, sizeof(int) * N_NODES * 2, stream);

    hist_kernel<<<(ETOT + 255) / 256, 256, 0, stream>>>(ei, counts);
    scan_kernel<<<1, 1024, 0, stream>>>(counts, row_start);
    scatter_kernel<<<(ETOT + 255) / 256, 256, 0, stream>>>(ei, row_start, cursor, csr_src);
    w2prep_kernel<<<(C1 * C2 + 255) / 256, 256, 0, stream>>>(W2, W2p);

    gemm1_kernel<<<N_NODES / 8, C1, 0, stream>>>(feats, W1, a1s, a1d, xw1b, s1s, s1d);
    agg1_kernel<<<N_NODES, C1, 0, stream>>>(xw1b, s1s, s1d, row_start, csr_src, b1, h1b);
    gemm2_mfma_kernel<<<(N_NODES / 16 + 3) / 4, 256, 0, stream>>>(h1b, W2p, a2s, a2d, xw2, s2s, s2d);
    agg2_kernel<<<N_NODES, C2, 0, stream>>>(xw2, s2s, s2d, row_start, csr_src, b2, x2);
    fc_main_kernel<<<N_NODES / 16, C2, 0, stream>>>(x2, fcw, fcb, out_main);
    pool_kernel<<<NB, C2, 0, stream>>>(x2, pooled);
    fc_pool_kernel<<<NB, C2, 0, stream>>>(pooled, fcw, fcb, out_pool);
}